// Round 5
// baseline (331.062 us; speedup 1.0000x reference)
//
#include <hip/hip_runtime.h>
#include <cstdint>
#include <cstddef>

#define NPTS 8192
#define NUM_CLASSES 5
#define XCOLS 10          // 3 coords + batch + feat + 5 seg
#define EPS2 225.0f
#define MIN_PTS 5
#define NGROUPS 10
#define BIGC 0x3fffffff
#define SLICE 65536       // per-group edge capacity (expect ~5.4k)

#define RTILE 1024        // rows per k_adj block
#define JT 32             // cols per k_adj block
#define RPT 4             // rows per thread

// ---------------- setup: pack coords+p2, group, init deg/gecnt ----------------
__global__ void k_setup(const float* __restrict__ x, float4* __restrict__ q,
                        int* __restrict__ grp, int* __restrict__ deg,
                        unsigned int* __restrict__ gecnt) {
    int i = blockIdx.x * blockDim.x + threadIdx.x;
    if (i < NGROUPS) gecnt[i] = 0u;
    if (i >= NPTS) return;
    const float* r = x + (size_t)i * XCOLS;
    float px = r[0], py = r[1], pz = r[2];
    int b = (int)r[3];
    float best = r[5]; int bc = 0;
    #pragma unroll
    for (int c = 1; c < NUM_CLASSES; c++) {
        float v = r[5 + c];
        if (v > best) { best = v; bc = c; }   // strict > keeps first max (jnp.argmax)
    }
    q[i] = make_float4(px, py, pz, px*px + py*py + pz*pz);
    grp[i] = b * NUM_CLASSES + bc;
    deg[i] = 1;          // self-adjacency (d2=0 < EPS2, same group)
}

// ---------------- adjacency -> per-group edge slices (j>i) + degree ----------
// grid = 8 row-tiles x 256 col-slices = 2048 blocks (~1150 active after
// triangle skip => ~4.5 blocks/CU of TLP). Thread owns 4 rows x 32 cols.
__global__ void __launch_bounds__(256) k_adj(
        const float4* __restrict__ q, const int* __restrict__ grp,
        unsigned int* __restrict__ edges, unsigned int* __restrict__ gecnt,
        int* __restrict__ deg) {
    int rt = blockIdx.x >> 8;        // 0..7
    int cs = blockIdx.x & 255;       // 0..255
    int i0 = rt * RTILE;
    int j0 = cs * JT;
    if (j0 + JT - 1 <= i0) return;   // no j>i possible in this block

    __shared__ float4 qs[JT];
    __shared__ int    gs[JT];
    int tid = threadIdx.x;
    if (tid < JT) { qs[tid] = q[j0 + tid]; gs[tid] = grp[j0 + tid]; }
    __syncthreads();

    float4 qi[RPT]; int gi[RPT]; int irow[RPT];
    #pragma unroll
    for (int r = 0; r < RPT; r++) {
        irow[r] = i0 + tid + 256 * r;
        qi[r] = q[irow[r]];
        gi[r] = grp[irow[r]];
    }

    unsigned int bits[RPT] = {0u, 0u, 0u, 0u};
    #pragma unroll
    for (int t = 0; t < JT; t++) {
        float4 qj = qs[t]; int gj = gs[t];          // wave-uniform broadcast
        #pragma unroll
        for (int r = 0; r < RPT; r++) {
            float d2 = qi[r].w + qj.w - 2.0f * (qi[r].x*qj.x + qi[r].y*qj.y + qi[r].z*qj.z);
            bool a = (gi[r] == gj) && (d2 < EPS2);
            bits[r] |= a ? (1u << t) : 0u;
        }
    }

    #pragma unroll
    for (int r = 0; r < RPT; r++) {
        int d = irow[r] - j0;                        // keep bits with j > irow
        unsigned int m = (d < 0) ? 0xffffffffu : ((d >= JT - 1) ? 0u : ~((2u << d) - 1u));
        unsigned int b = bits[r] & m;
        int c = __popc(b);
        if (c > 0) {
            atomicAdd(&deg[irow[r]], c);
            unsigned int base = atomicAdd(&gecnt[gi[r]], (unsigned int)c);
            unsigned int* eg = edges + (size_t)gi[r] * SLICE;
            unsigned int uhi = (unsigned int)irow[r] << 13;
            while (b) {
                int bb = __ffs(b) - 1;
                b &= b - 1;
                int j = j0 + bb;
                if (base < SLICE) eg[base] = uhi | (unsigned int)j;
                base++;
                atomicAdd(&deg[j], 1);
            }
        }
    }
}

// ---------------- LDS union-find: path-halving find + min-hook union --------
__device__ __forceinline__ int lfind(volatile int* p, int x) {
    while (true) {
        int px = p[x];
        if (px == x) return x;
        int pp = p[px];
        if (pp == px) return px;
        p[x] = pp;            // monotone-decreasing ancestor: race-safe
        x = pp;
    }
}

__device__ __forceinline__ void umin(int* p, int u, int v) {
    while (true) {
        u = lfind(p, u); v = lfind(p, v);
        if (u == v) return;
        int hi = u > v ? u : v;
        int lo = u + v - hi;
        int old = atomicMin(&p[hi], lo);   // always monotone progress
        if (old == hi) return;             // we hooked the root
        u = lo; v = old;                   // must still merge lo with old
    }
}

// ---------------- per-group: union + rank + border + final ------------------
// one block per group; streams only this group's edge slice
__global__ void __launch_bounds__(1024) k_group(
        const unsigned int* __restrict__ edges, const unsigned int* __restrict__ gecnt,
        const int* __restrict__ deg, const int* __restrict__ grp,
        const float* __restrict__ x, float* __restrict__ out) {
    __shared__ int spar[NPTS];                       // parent -> later ccid (32 KB)
    __shared__ int scid[NPTS];                       // cid of reps (32 KB)
    __shared__ int lbmin[NPTS];                      // border min cid (32 KB)
    __shared__ unsigned char sgrp[NPTS];             // 8 KB
    __shared__ unsigned long long corebm[NPTS/64];   // 1 KB
    __shared__ unsigned long long repbm[NPTS/64];    // 1 KB
    __shared__ int wpart[16];
    int g = blockIdx.x;
    int tid = threadIdx.x;
    const unsigned int* eg = edges + (size_t)g * SLICE;
    unsigned int Eu = gecnt[g];
    int E = (Eu > (unsigned)SLICE) ? SLICE : (int)Eu;

    for (int i = tid; i < NPTS; i += 1024) {
        spar[i] = i; lbmin[i] = BIGC; sgrp[i] = (unsigned char)grp[i];
    }
    for (int w = tid; w < NPTS/64; w += 1024) { corebm[w] = 0ull; repbm[w] = 0ull; }
    __syncthreads();
    for (int i = tid; i < NPTS; i += 1024)
        if (deg[i] >= MIN_PTS) atomicOr(&corebm[i >> 6], 1ull << (i & 63));
    __syncthreads();

    auto corebit = [&](int v) -> bool { return (corebm[v >> 6] >> (v & 63)) & 1ull; };

    // union pass over this group's core-core edges (min-hook)
    for (int e = tid; e < E; e += 1024) {
        unsigned int pk = eg[e];
        int u = (int)(pk >> 13), v = (int)(pk & 8191u);
        if (!corebit(u) || !corebit(v)) continue;
        umin(spar, u, v);
    }
    __syncthreads();
    // flatten core nodes (monotone, race-safe)
    for (int i = tid; i < NPTS; i += 1024)
        if (corebit(i)) spar[i] = lfind(spar, i);
    __syncthreads();
    // rep bitmap (this group's reps only)
    for (int i = tid; i < NPTS; i += 1024)
        if (corebit(i) && spar[i] == i && (int)sgrp[i] == g)
            atomicOr(&repbm[i >> 6], 1ull << (i & 63));
    __syncthreads();
    // hierarchical rank: wave wv owns words 8wv..8wv+7
    int wv = tid >> 6, lane = tid & 63;
    if (lane == 0) {
        int s = 0;
        #pragma unroll
        for (int k = 0; k < 8; k++) s += __popcll(repbm[wv * 8 + k]);
        wpart[wv] = s;
    }
    __syncthreads();
    if (tid == 0) {
        int acc = 0;
        #pragma unroll
        for (int w = 0; w < 16; w++) { int t = wpart[w]; wpart[w] = acc; acc += t; }
    }
    __syncthreads();
    {
        int running = wpart[wv];
        #pragma unroll
        for (int k = 0; k < 8; k++) {
            unsigned long long bb = repbm[wv * 8 + k];
            if ((bb >> lane) & 1ull)
                scid[(wv * 8 + k) * 64 + lane] = running + __popcll(bb & ((1ull << lane) - 1ull));
            running += __popcll(bb);
        }
    }
    __syncthreads();
    // ccid per node -> overwrite spar (read-all, barrier, write-all)
    int cc[NPTS / 1024];
    #pragma unroll
    for (int k = 0; k < NPTS / 1024; k++) {
        int i = tid + k * 1024;
        cc[k] = (corebit(i) && (int)sgrp[i] == g) ? scid[spar[i]] : BIGC;
    }
    __syncthreads();
    #pragma unroll
    for (int k = 0; k < NPTS / 1024; k++) spar[tid + k * 1024] = cc[k];
    __syncthreads();
    // border pass: min core-neighbor cid
    for (int e = tid; e < E; e += 1024) {
        unsigned int pk = eg[e];
        int u = (int)(pk >> 13), v = (int)(pk & 8191u);
        int cu = spar[u], cv = spar[v];
        if (cu == BIGC && cv != BIGC) atomicMin(&lbmin[u], cv);
        if (cv == BIGC && cu != BIGC) atomicMin(&lbmin[v], cu);
    }
    __syncthreads();
    // final labels + clustered output for this group's nodes
    for (int i = tid; i < NPTS; i += 1024) {
        if ((int)sgrp[i] != g) continue;
        int c = spar[i];
        int lbl = (c != BIGC) ? c : ((lbmin[i] < BIGC) ? lbmin[i] : -1);
        out[i] = (float)lbl;
        const float* r = x + (size_t)i * XCOLS;
        float* o = out + NPTS + (size_t)i * 5;
        bool keep = lbl >= 0;
        #pragma unroll
        for (int c5 = 0; c5 < 5; c5++) o[c5] = keep ? r[c5] : 0.0f;
    }
}

extern "C" void kernel_launch(void* const* d_in, const int* in_sizes, int n_in,
                              void* d_out, int out_size, void* d_ws, size_t ws_size,
                              hipStream_t stream) {
    const float* x = (const float*)d_in[0];
    float* out = (float*)d_out;
    char* ws = (char*)d_ws;

    // workspace layout (~2.9 MB)
    float4* q          = (float4*)(ws);                  // 131072 B
    int* grp           = (int*)(ws + 131072);            // 32768
    int* deg           = (int*)(ws + 163840);            // 32768
    unsigned int* gecnt= (unsigned int*)(ws + 196608);   // 256
    unsigned int* edges= (unsigned int*)(ws + 196864);   // 10*SLICE*4 = 2.62 MB

    k_setup <<<NPTS / 256, 256, 0, stream>>>(x, q, grp, deg, gecnt);
    k_adj   <<<8 * 256, 256, 0, stream>>>(q, grp, edges, gecnt, deg);
    k_group <<<NGROUPS, 1024, 0, stream>>>(edges, gecnt, deg, grp, x, out);
}

// Round 6
// 122.786 us; speedup vs baseline: 2.6963x; 2.6963x over previous
//
#include <hip/hip_runtime.h>
#include <cstdint>
#include <cstddef>

#define NPTS 8192
#define NUM_CLASSES 5
#define XCOLS 10          // 3 coords + batch + feat + 5 seg
#define EPS2 225.0f
#define MIN_PTS 5
#define NGROUPS 10
#define BIGC 0x3fffffff

#define BANDS 8           // row bands of 1024 rows, one edge region + counter each
#define BANDROWS 1024
#define BANDCAP 32768     // edges per band region (expect ~5k)
#define CPAD 64           // band counters padded 64 ints (256 B) apart
#define JT 32             // cols staged per k_adj block
#define RPT 4             // rows per thread

#define ELCAP 7168        // per-group core-core edges in LDS (expect ~5k)
#define EBCAP 2048        // per-group core-noncore edges in LDS (expect ~500)
#define ROUNDS 24

// ---------------- setup: pack coords+p2, group, init deg / band counters -----
__global__ void k_setup(const float* __restrict__ x, float4* __restrict__ q,
                        int* __restrict__ grp, int* __restrict__ deg,
                        unsigned int* __restrict__ bandcnt) {
    int i = blockIdx.x * blockDim.x + threadIdx.x;
    if (i < BANDS * CPAD) bandcnt[i] = 0u;
    if (i >= NPTS) return;
    const float* r = x + (size_t)i * XCOLS;
    float px = r[0], py = r[1], pz = r[2];
    int b = (int)r[3];
    float best = r[5]; int bc = 0;
    #pragma unroll
    for (int c = 1; c < NUM_CLASSES; c++) {
        float v = r[5 + c];
        if (v > best) { best = v; bc = c; }   // strict > keeps first max (jnp.argmax)
    }
    q[i] = make_float4(px, py, pz, px*px + py*py + pz*pz);
    grp[i] = b * NUM_CLASSES + bc;
    deg[i] = 1;          // self-adjacency (d2=0 < EPS2, same group)
}

// ---------------- adjacency -> banded edge list (j>i) + degree ---------------
// grid = 8 row-bands x 256 col-slices; block 256 thr; thread owns 4 rows x 32 cols.
// Emission: wave shfl-scan -> block scan -> ONE atomicAdd per block on a
// band-private padded counter (kills the R5 same-line atomic serialization).
__global__ void __launch_bounds__(256) k_adj(
        const float4* __restrict__ q, const int* __restrict__ grp,
        unsigned int* __restrict__ edges, unsigned int* __restrict__ bandcnt,
        int* __restrict__ deg) {
    int rt = blockIdx.x >> 8;        // 0..7 row band
    int cs = blockIdx.x & 255;       // 0..255 col slice
    int i0 = rt * BANDROWS;
    int j0 = cs * JT;
    if (j0 + JT - 1 <= i0) return;   // no j>i possible in this block

    __shared__ float4 qs[JT];
    __shared__ int    gs[JT];
    __shared__ int    warr[4], woff[4], bbase_s;
    int tid = threadIdx.x;
    if (tid < JT) { qs[tid] = q[j0 + tid]; gs[tid] = grp[j0 + tid]; }
    __syncthreads();

    float4 qi[RPT]; int gi[RPT]; int irow[RPT];
    #pragma unroll
    for (int r = 0; r < RPT; r++) {
        irow[r] = i0 + tid + 256 * r;
        qi[r] = q[irow[r]];
        gi[r] = grp[irow[r]];
    }

    unsigned int bits[RPT] = {0u, 0u, 0u, 0u};
    #pragma unroll
    for (int t = 0; t < JT; t++) {
        float4 qj = qs[t]; int gj = gs[t];          // wave-uniform broadcast
        #pragma unroll
        for (int r = 0; r < RPT; r++) {
            float d2 = qi[r].w + qj.w - 2.0f * (qi[r].x*qj.x + qi[r].y*qj.y + qi[r].z*qj.z);
            bool a = (gi[r] == gj) && (d2 < EPS2);
            bits[r] |= a ? (1u << t) : 0u;
        }
    }

    int rc[RPT]; int cnt = 0;
    #pragma unroll
    for (int r = 0; r < RPT; r++) {
        int d = irow[r] - j0;                        // keep bits with j > irow
        unsigned int m = (d < 0) ? 0xffffffffu : ((d >= JT - 1) ? 0u : (0xffffffffu << (d + 1)));
        bits[r] &= m;
        rc[r] = __popc(bits[r]);
        cnt += rc[r];
    }

    // wave inclusive scan of cnt
    int lane = tid & 63, wv = tid >> 6;
    int incl = cnt;
    #pragma unroll
    for (int d = 1; d < 64; d <<= 1) {
        int o = __shfl_up(incl, d);
        if (lane >= d) incl += o;
    }
    if (lane == 63) warr[wv] = incl;
    __syncthreads();
    if (tid == 0) {
        int acc = 0;
        #pragma unroll
        for (int w = 0; w < 4; w++) { woff[w] = acc; acc += warr[w]; }
        bbase_s = (acc > 0) ? (int)atomicAdd(&bandcnt[rt * CPAD], (unsigned int)acc) : 0;
    }
    __syncthreads();

    int pos = bbase_s + woff[wv] + (incl - cnt);
    unsigned int* eg = edges + (size_t)rt * BANDCAP;
    #pragma unroll
    for (int r = 0; r < RPT; r++) {
        if (rc[r] > 0) {
            atomicAdd(&deg[irow[r]], rc[r]);
            unsigned int tag = ((unsigned int)gi[r] << 26) | ((unsigned int)irow[r] << 13);
            unsigned int b = bits[r];
            while (b) {
                int bb = __ffs(b) - 1;
                b &= b - 1;
                int j = j0 + bb;
                if (pos < BANDCAP) eg[pos] = tag | (unsigned int)j;
                pos++;
                atomicAdd(&deg[j], 1);
            }
        }
    }
}

// ---------------- per-group: prefilter -> SV rounds -> rank -> border -> out --
// one block (1024 thr) per group; all graph state in LDS.
__global__ void __launch_bounds__(1024) k_group(
        const unsigned int* __restrict__ edges, const unsigned int* __restrict__ bandcnt,
        const int* __restrict__ deg, const int* __restrict__ grp,
        const float* __restrict__ x, float* __restrict__ out) {
    __shared__ int spar[NPTS];                       // labels -> later ccid (32 KB)
    __shared__ int sbuf[NPTS];                       // scid then lbmin (32 KB)
    __shared__ unsigned char sgrp[NPTS];             // 8 KB
    __shared__ unsigned long long corebm[NPTS/64];   // 1 KB
    __shared__ unsigned long long repbm[NPTS/64];    // 1 KB
    __shared__ unsigned int eL[ELCAP];               // core-core edges (28 KB)
    __shared__ unsigned int eB[EBCAP];               // core-noncore edges (8 KB)
    __shared__ int nL, nB, sflag, wpart[16];

    int g = blockIdx.x;
    int tid = threadIdx.x, lane = tid & 63, wv = tid >> 6;

    for (int i = tid; i < NPTS; i += 1024) { spar[i] = i; sgrp[i] = (unsigned char)grp[i]; }
    // core bitmap via ballot (no LDS atomics)
    for (int w = wv; w < NPTS/64; w += 16) {
        int i = w * 64 + lane;
        unsigned long long bm = __ballot(deg[i] >= MIN_PTS);
        if (lane == 0) corebm[w] = bm;
    }
    if (tid == 0) { nL = 0; nB = 0; }
    __syncthreads();

    auto corebit = [&](int v) -> bool { return (corebm[v >> 6] >> (v & 63)) & 1ull; };

    // prefilter this group's edges into LDS (wave-aggregated appends)
    for (int b = 0; b < BANDS; b++) {
        unsigned int Eu = bandcnt[b * CPAD];
        int E = (Eu > (unsigned)BANDCAP) ? BANDCAP : (int)Eu;
        const unsigned int* eg = edges + (size_t)b * BANDCAP;
        for (int e0 = 0; e0 < E; e0 += 1024) {
            int e = e0 + tid;
            unsigned int pk = (e < E) ? eg[e] : 0xffffffffu;
            bool mine = (e < E) && ((int)(pk >> 26) == g);
            int u = (int)((pk >> 13) & 8191u), v = (int)(pk & 8191u);
            bool cu = mine && corebit(u), cv = mine && corebit(v);
            bool isL = cu && cv;
            bool isB = mine && (cu != cv);
            unsigned long long mL = __ballot(isL);
            int cL = __popcll(mL);
            int base = 0;
            if (cL) {
                if (lane == 0) base = atomicAdd(&nL, cL);
                base = __shfl(base, 0);
                if (isL) {
                    int idx = base + __popcll(mL & ((1ull << lane) - 1ull));
                    if (idx < ELCAP) eL[idx] = pk & 0x3ffffffu;
                }
            }
            unsigned long long mB = __ballot(isB);
            int cB = __popcll(mB);
            if (cB) {
                if (lane == 0) base = atomicAdd(&nB, cB);
                base = __shfl(base, 0);
                if (isB) {
                    int idx = base + __popcll(mB & ((1ull << lane) - 1ull));
                    if (idx < EBCAP) eB[idx] = pk & 0x3ffffffu;
                }
            }
        }
    }
    __syncthreads();
    int NL = (nL > ELCAP) ? ELCAP : nL;
    int NB = (nB > EBCAP) ? EBCAP : nB;

    // Shiloach-Vishkin-style rounds: hook-to-min + pointer jump, barriered.
    // Monotone-decreasing labels; fixpoint = component-min for all core nodes.
    for (int r = 0; r < ROUNDS; r++) {
        if (tid == 0) sflag = 0;
        __syncthreads();
        for (int k = tid; k < NL; k += 1024) {
            unsigned int pk = eL[k];
            int u = (int)((pk >> 13) & 8191u), v = (int)(pk & 8191u);
            int a = spar[u], b2 = spar[v];
            if (a < b2)      { int old = atomicMin(&spar[v], a);  if (old > a)  sflag = 1; }
            else if (b2 < a) { int old = atomicMin(&spar[u], b2); if (old > b2) sflag = 1; }
        }
        __syncthreads();
        for (int i = tid; i < NPTS; i += 1024) {
            int s = spar[i]; int s2 = spar[s];
            if (s2 < s) { spar[i] = s2; sflag = 1; }
        }
        __syncthreads();
        if (!sflag) break;
    }

    // rep bitmap + hierarchical rank (cid = rank of rep index within group)
    for (int w = wv; w < NPTS/64; w += 16) {
        int i = w * 64 + lane;
        bool isr = corebit(i) && (spar[i] == i) && ((int)sgrp[i] == g);
        unsigned long long bm = __ballot(isr);
        if (lane == 0) repbm[w] = bm;
    }
    __syncthreads();
    if (lane == 0) {
        int s = 0;
        #pragma unroll
        for (int k = 0; k < 8; k++) s += __popcll(repbm[wv * 8 + k]);
        wpart[wv] = s;
    }
    __syncthreads();
    if (tid == 0) {
        int acc = 0;
        #pragma unroll
        for (int w = 0; w < 16; w++) { int t = wpart[w]; wpart[w] = acc; acc += t; }
    }
    __syncthreads();
    {
        int running = wpart[wv];
        #pragma unroll
        for (int k = 0; k < 8; k++) {
            unsigned long long bb = repbm[wv * 8 + k];
            if ((bb >> lane) & 1ull)
                sbuf[(wv * 8 + k) * 64 + lane] = running + __popcll(bb & ((1ull << lane) - 1ull));
            running += __popcll(bb);
        }
    }
    __syncthreads();
    // ccid per node -> overwrite spar (read-all, barrier, write-all)
    int cc[NPTS / 1024];
    #pragma unroll
    for (int k = 0; k < NPTS / 1024; k++) {
        int i = tid + k * 1024;
        cc[k] = (corebit(i) && (int)sgrp[i] == g) ? sbuf[spar[i]] : BIGC;
    }
    __syncthreads();
    #pragma unroll
    for (int k = 0; k < NPTS / 1024; k++) spar[tid + k * 1024] = cc[k];
    // reuse sbuf as border-min
    #pragma unroll
    for (int k = 0; k < NPTS / 1024; k++) sbuf[tid + k * 1024] = BIGC;
    __syncthreads();
    // border: min adjacent core cid for non-core endpoints
    for (int k = tid; k < NB; k += 1024) {
        unsigned int pk = eB[k];
        int u = (int)((pk >> 13) & 8191u), v = (int)(pk & 8191u);
        int cu = spar[u], cv = spar[v];
        if (cu == BIGC && cv != BIGC)      atomicMin(&sbuf[u], cv);
        else if (cv == BIGC && cu != BIGC) atomicMin(&sbuf[v], cu);
    }
    __syncthreads();
    // final labels + clustered output for this group's nodes
    for (int i = tid; i < NPTS; i += 1024) {
        if ((int)sgrp[i] != g) continue;
        int c = spar[i];
        int lbl = (c != BIGC) ? c : ((sbuf[i] < BIGC) ? sbuf[i] : -1);
        out[i] = (float)lbl;
        const float* r = x + (size_t)i * XCOLS;
        float* o = out + NPTS + (size_t)i * 5;
        bool keep = lbl >= 0;
        #pragma unroll
        for (int c5 = 0; c5 < 5; c5++) o[c5] = keep ? r[c5] : 0.0f;
    }
}

extern "C" void kernel_launch(void* const* d_in, const int* in_sizes, int n_in,
                              void* d_out, int out_size, void* d_ws, size_t ws_size,
                              hipStream_t stream) {
    const float* x = (const float*)d_in[0];
    float* out = (float*)d_out;
    char* ws = (char*)d_ws;

    // workspace layout (~1.25 MB)
    float4* q            = (float4*)(ws);                   // 131072 B
    int* grp             = (int*)(ws + 131072);             // 32768
    int* deg             = (int*)(ws + 163840);             // 32768
    unsigned int* bandcnt= (unsigned int*)(ws + 196608);    // 8*64*4 = 2048
    unsigned int* edges  = (unsigned int*)(ws + 198656);    // 8*32768*4 = 1 MB

    k_setup <<<NPTS / 256, 256, 0, stream>>>(x, q, grp, deg, bandcnt);
    k_adj   <<<BANDS * 256, 256, 0, stream>>>(q, grp, edges, bandcnt, deg);
    k_group <<<NGROUPS, 1024, 0, stream>>>(edges, bandcnt, deg, grp, x, out);
}